// Round 4
// baseline (205.297 us; speedup 1.0000x reference)
//
#include <hip/hip_runtime.h>
#include <cstdint>
#include <cstddef>

typedef unsigned short u16;
typedef uint32_t u32;
typedef __bf16 bf16x8 __attribute__((ext_vector_type(8)));
typedef float f32x4 __attribute__((ext_vector_type(4)));
typedef float f32x16 __attribute__((ext_vector_type(16)));

typedef __attribute__((address_space(1))) void gvoid;
typedef __attribute__((address_space(3))) void lvoid;

__device__ __forceinline__ void g2l16(const void* g, void* l) {
    __builtin_amdgcn_global_load_lds((gvoid*)g, (lvoid*)l, 16, 0, 0);
}

__device__ __forceinline__ u16 f2bf(float f) {
    union { float f; uint32_t u; } v;
    v.f = f;
    uint32_t r = (v.u + 0x7FFFu + ((v.u >> 16) & 1u)) >> 16;
    return (u16)r;
}

// ---------------- fp32 -> bf16 conversion of x, Wqk, Wv, Wo into ws ----------------
__global__ __launch_bounds__(256)
void cvt_kernel(const float* __restrict__ x, const float* __restrict__ wqk,
                const float* __restrict__ wv, const float* __restrict__ wo,
                u16* __restrict__ out) {
    int i = (blockIdx.x * 256 + threadIdx.x) * 4;
    const float* src;
    int off;
    if (i < 4194304)      { src = x;   off = 0; }
    else if (i < 5242880) { src = wqk; off = 4194304; }
    else if (i < 6291456) { src = wv;  off = 5242880; }
    else                  { src = wo;  off = 6291456; }
    float4 v = *(const float4*)(src + (i - off));
    ushort4 o;
    o.x = f2bf(v.x); o.y = f2bf(v.y); o.z = f2bf(v.z); o.w = f2bf(v.w);
    *(ushort4*)(out + i) = o;
}

// ---------------- bf16 GEMM: out[m][n] = sum_k A[m][k]*Bw[n][k] + bias[n] ----------------
// BM=128, BN=128, BK=32, 2-phase double-buffered staging, 256 threads (4 waves 2x2).
// MODE 0: Kpack fragment-major layout [bh][kt][dc][lane][8]
// MODE 1: Vpack fragment-major layout [bh][kt][kk][ch][lane][8]
// MODE 2: f32 row-major out [4096][1024]
template <int MODE>
__global__ __launch_bounds__(256)
void gemm_kernel(const u16* __restrict__ A, const u16* __restrict__ Bw,
                 const float* __restrict__ bias, void* __restrict__ outp) {
    __shared__ __align__(16) u16 As[2][128 * 32];
    __shared__ __align__(16) u16 Bs[2][128 * 32];
    const int bid = blockIdx.x;
    const int m0 = (bid >> 3) * 128;
    const int n0 = (bid & 7) * 128;
    const int t = threadIdx.x;
    const int lane = t & 63;
    const int wid = t >> 6;
    const int wr = wid >> 1, wc = wid & 1;
    const int l15 = lane & 15, l4 = lane >> 4;

    f32x4 acc[4][4] = {};

    auto stage = [&](int buf, int kt) {
        const int kbase = kt * 32;
#pragma unroll
        for (int c = 0; c < 2; ++c) {
            const int p = c * 4096 + t * 16;      // byte pos
            const int row = p >> 6;
            const int koff = (p & 63) >> 1;       // elems
            g2l16(A  + (size_t)(m0 + row) * 1024 + kbase + koff, (char*)As[buf] + p);
            g2l16(Bw + (size_t)(n0 + row) * 1024 + kbase + koff, (char*)Bs[buf] + p);
        }
    };

    stage(0, 0);
    asm volatile("s_waitcnt vmcnt(0)" ::: "memory");
    __syncthreads();

    int cur = 0;
    for (int kt = 0; kt < 32; ++kt) {
        if (kt + 1 < 32) stage(cur ^ 1, kt + 1);
        bf16x8 af[4], bfr[4];
#pragma unroll
        for (int mi = 0; mi < 4; ++mi)
            af[mi] = *(const bf16x8*)((const char*)As[cur] + (wr * 64 + mi * 16 + l15) * 64 + l4 * 16);
#pragma unroll
        for (int ni = 0; ni < 4; ++ni)
            bfr[ni] = *(const bf16x8*)((const char*)Bs[cur] + (wc * 64 + ni * 16 + l15) * 64 + l4 * 16);
#pragma unroll
        for (int mi = 0; mi < 4; ++mi)
#pragma unroll
            for (int ni = 0; ni < 4; ++ni)
                acc[mi][ni] = __builtin_amdgcn_mfma_f32_16x16x32_bf16(af[mi], bfr[ni], acc[mi][ni], 0, 0, 0);
        asm volatile("s_waitcnt vmcnt(0)" ::: "memory");
        __syncthreads();
        cur ^= 1;
    }

    const int mbase = m0 + wr * 64 + l4 * 4;
    const int nbase = n0 + wc * 64 + l15;
#pragma unroll
    for (int ni = 0; ni < 4; ++ni) {
        const int n = nbase + ni * 16;
        const float bv = bias[n];
#pragma unroll
        for (int mi = 0; mi < 4; ++mi) {
            const int mrow = mbase + mi * 16;
            if (MODE == 1) {
                // Vpack: element (t,d) -> [bh][tt>>5][(tt>>4)&1][d>>5][((tt>>3)&1)*32+(d&31)][tt&7]
                const int tt = mrow & 2047, b_ = mrow >> 11;
                const int h_ = n >> 8, dd = n & 255;
                const size_t addr =
                    ((size_t)((((b_ * 4 + h_) * 64 + (tt >> 5)) * 2 + ((tt >> 4) & 1)) * 8 + (dd >> 5))) * 512
                    + (((tt >> 3) & 1) * 32 + (dd & 31)) * 8 + (tt & 7);
                ushort4 w;
                w.x = f2bf(acc[mi][ni][0] + bv);
                w.y = f2bf(acc[mi][ni][1] + bv);
                w.z = f2bf(acc[mi][ni][2] + bv);
                w.w = f2bf(acc[mi][ni][3] + bv);
                *(ushort4*)((u16*)outp + addr) = w;
            } else if (MODE == 0) {
                // Kpack: element (t,d) -> [bh][tt>>5][d>>4][((d>>3)&1)*32+(tt&31)][d&7]
#pragma unroll
                for (int r = 0; r < 4; ++r) {
                    const int t2 = mrow + r;
                    const int tt = t2 & 2047, b_ = t2 >> 11;
                    const int h_ = n >> 8, dd = n & 255;
                    const size_t addr =
                        ((size_t)(((b_ * 4 + h_) * 64 + (tt >> 5)) * 16 + (dd >> 4))) * 512
                        + (((dd >> 3) & 1) * 32 + (tt & 31)) * 8 + (dd & 7);
                    ((u16*)outp)[addr] = f2bf(acc[mi][ni][r] + bv);
                }
            } else {
#pragma unroll
                for (int r = 0; r < 4; ++r)
                    ((float*)outp)[(size_t)(mrow + r) * 1024 + n] = acc[mi][ni][r] + bv;
            }
        }
    }
}

// ---------------- spiral flash attention: 1-wave blocks, fragment-major direct loads ----------------
// Grid 1280 = 8 bh x 160 chunks. Column c (32 queries) has n=c+1 k-tiles, split into
// nch = 1+(c>>4) chunks of <=16 tiles. Each block: private online-softmax over its chunk.
// Single-chunk cols write normalized output; others write raw partials (diag chunk ->
// attnb region, rest -> scratch slots) + (m,l) into d_out (dead until gemm2).
__global__ __launch_bounds__(64, 2)
void attn_kernel(const u16* __restrict__ kpack, const u16* __restrict__ vpack,
                 u16* __restrict__ attnb, u16* __restrict__ partO, float* __restrict__ mlout) {
    const int bid = blockIdx.x;
    const int bh = bid & 7;                    // head pinned per XCD for L2 locality
    const int u = 159 - (bid >> 3);            // longest chunks dispatched first
    int g, B;
    if (u < 16)      { g = 0; B = 0;  }
    else if (u < 48) { g = 1; B = 16; }
    else if (u < 96) { g = 2; B = 48; }
    else             { g = 3; B = 96; }
    const int w = u - B;
    const int dv = (g == 0) ? w : (g == 1) ? (w >> 1) : (g == 2) ? (w / 3) : (w >> 2);
    const int k = w - dv * (g + 1);
    const int c = 16 * g + dv;                 // query column (32 q)
    const int n = c + 1;                       // total k-tiles for this column
    const int t0 = 16 * k;
    const int t1 = (k == g) ? n : t0 + 16;
    const bool single = (g == 0);
    const bool diag = (k == g);

    const int b = bh >> 2, h = bh & 3;
    const int s = (h == 0) ? 1 : ((h == 1) ? 3 : ((h == 2) ? 7 : 13));
    const float rs = 1.0f / (float)s;
    const int l = threadIdx.x;
    const int l31 = l & 31, h5 = l >> 5;
    const int q = c * 32 + l31;                // this lane's query row
    const float c2 = 0.09016844f;              // (1/16) * log2(e)
    const int lane8 = l * 8;

    // Q fragments from Kpack tile c: coalesced base + lane*16
    bf16x8 qf[16];
    {
        const u16* qb = kpack + ((size_t)(bh * 64 + c)) * 8192 + lane8;
#pragma unroll
        for (int dc = 0; dc < 16; ++dc)
            qf[dc] = *(const bf16x8*)(qb + dc * 512);
    }

    f32x16 o[8] = {};
    float mrun = -3.0e38f, lrun = 0.0f;

    for (int kt = t0; kt < t1; ++kt) {
        const int key0 = kt * 32;

        // S^T = K * Q^T, K fragments coalesced from Kpack
        const u16* kb = kpack + ((size_t)(bh * 64 + kt)) * 8192 + lane8;
        f32x16 sacc = {};
#pragma unroll
        for (int dc = 0; dc < 16; ++dc) {
            const bf16x8 kf = *(const bf16x8*)(kb + dc * 512);
            sacc = __builtin_amdgcn_mfma_f32_32x32x16_bf16(kf, qf[dc], sacc, 0, 0, 0);
        }

        // mask + online softmax (state lane-local for query q)
        const int ebase = (key0 - q + 3072) & 2047;
        float sv[16];
        float tmax = -3.0e38f;
#pragma unroll
        for (int r = 0; r < 16; ++r) {
            const int km = (r & 3) + 8 * (r >> 2) + 4 * h5;   // key row within 32-key tile
            int e = ebase + km;
            if (e >= 2048) e -= 2048;
            const int md = e - s * (int)((float)e * rs);
            const bool v = ((key0 + km) <= q) && (md == 0);
            sv[r] = v ? sacc[r] : -3.0e38f;
            tmax = fmaxf(tmax, sv[r]);
        }
        tmax = fmaxf(tmax, __shfl_xor(tmax, 32, 64));
        if (!__all(tmax <= mrun + 8.0f)) {     // defer-max
            const float mnew = fmaxf(mrun, tmax);
            const float fsc = __builtin_amdgcn_exp2f((mrun - mnew) * c2);
            lrun *= fsc;
#pragma unroll
            for (int ch = 0; ch < 8; ++ch)
#pragma unroll
                for (int r = 0; r < 16; ++r)
                    o[ch][r] *= fsc;
            mrun = mnew;
        }
        float psum = 0.0f;
#pragma unroll
        for (int r = 0; r < 16; ++r) {
            const float p = (sv[r] > -1.0e37f) ? __builtin_amdgcn_exp2f((sv[r] - mrun) * c2) : 0.0f;
            sv[r] = p;
            psum += p;
        }
        lrun += psum;

        // P -> bf16 fragments: cvt_pk + permlane32_swap (T12)
        uint32_t w0, w1, w2, w3, w4, w5, w6, w7;
        asm("v_cvt_pk_bf16_f32 %0,%1,%2" : "=v"(w0) : "v"(sv[0]),  "v"(sv[1]));
        asm("v_cvt_pk_bf16_f32 %0,%1,%2" : "=v"(w1) : "v"(sv[2]),  "v"(sv[3]));
        asm("v_cvt_pk_bf16_f32 %0,%1,%2" : "=v"(w2) : "v"(sv[4]),  "v"(sv[5]));
        asm("v_cvt_pk_bf16_f32 %0,%1,%2" : "=v"(w3) : "v"(sv[6]),  "v"(sv[7]));
        asm("v_cvt_pk_bf16_f32 %0,%1,%2" : "=v"(w4) : "v"(sv[8]),  "v"(sv[9]));
        asm("v_cvt_pk_bf16_f32 %0,%1,%2" : "=v"(w5) : "v"(sv[10]), "v"(sv[11]));
        asm("v_cvt_pk_bf16_f32 %0,%1,%2" : "=v"(w6) : "v"(sv[12]), "v"(sv[13]));
        asm("v_cvt_pk_bf16_f32 %0,%1,%2" : "=v"(w7) : "v"(sv[14]), "v"(sv[15]));
        asm("v_permlane32_swap_b32 %0, %1" : "+v"(w0), "+v"(w2));
        asm("v_permlane32_swap_b32 %0, %1" : "+v"(w1), "+v"(w3));
        asm("v_permlane32_swap_b32 %0, %1" : "+v"(w4), "+v"(w6));
        asm("v_permlane32_swap_b32 %0, %1" : "+v"(w5), "+v"(w7));
        union { uint32_t u[4]; bf16x8 v; } p0u, p1u;
        p0u.u[0] = w0; p0u.u[1] = w1; p0u.u[2] = w2; p0u.u[3] = w3;
        p1u.u[0] = w4; p1u.u[1] = w5; p1u.u[2] = w6; p1u.u[3] = w7;

        // O^T += V^T * P^T, V fragments coalesced from Vpack
        const u16* vb = vpack + ((size_t)(bh * 64 + kt)) * 8192 + lane8;
#pragma unroll
        for (int kk = 0; kk < 2; ++kk) {
            const bf16x8 pf = kk ? p1u.v : p0u.v;
#pragma unroll
            for (int ch = 0; ch < 8; ++ch) {
                const bf16x8 vf = *(const bf16x8*)(vb + (kk * 8 + ch) * 512);
                o[ch] = __builtin_amdgcn_mfma_f32_32x32x16_bf16(vf, pf, o[ch], 0, 0, 0);
            }
        }
    }

    lrun += __shfl_xor(lrun, 32, 64);

    float scale = 1.0f;
    u16* ab;
    if (single) {
        scale = (lrun > 0.0f) ? 1.0f / lrun : 0.0f;
        ab = attnb + (size_t)(b * 2048 + q) * 1024 + h * 256;
    } else {
        const int mlidx = bh * 160 + c + 8 * g * (g - 1) + g * dv + k;
        if (h5 == 0) {
            mlout[(size_t)mlidx * 64 + l31 * 2]     = mrun;
            mlout[(size_t)mlidx * 64 + l31 * 2 + 1] = lrun;
        }
        if (diag) {
            ab = attnb + (size_t)(b * 2048 + q) * 1024 + h * 256;
        } else {
            const int slot = bh * 96 + 8 * g * (g - 1) + g * dv + k;
            ab = partO + (size_t)slot * 8192 + l31 * 256;
        }
    }

#pragma unroll
    for (int ch = 0; ch < 8; ++ch) {
#pragma unroll
        for (int g2 = 0; g2 < 4; ++g2) {
            ushort4 wv4;
            wv4.x = f2bf(o[ch][g2 * 4 + 0] * scale);
            wv4.y = f2bf(o[ch][g2 * 4 + 1] * scale);
            wv4.z = f2bf(o[ch][g2 * 4 + 2] * scale);
            wv4.w = f2bf(o[ch][g2 * 4 + 3] * scale);
            *(ushort4*)(ab + ch * 32 + 8 * g2 + 4 * h5) = wv4;
        }
    }
}

// ---------------- combine partials for columns c in [16,64) ----------------
__global__ __launch_bounds__(256)
void combine_kernel(const u16* __restrict__ partO, const float* __restrict__ mlbuf,
                    u16* __restrict__ attnb) {
    const int bid = blockIdx.x;            // 384 = 8 bh x 48 cols
    const int bh = bid & 7;
    const int c = 16 + (bid >> 3);
    const int b = bh >> 2, h = bh & 3;
    const int g = c >> 4, dv = c & 15;
    const int nch = g + 1;
    const int slotB = bh * 96 + 8 * g * (g - 1) + g * dv;
    const int mlB   = bh * 160 + c + 8 * g * (g - 1) + g * dv;
    const int t = threadIdx.x;
    const int q = t >> 3, dp = (t & 7) * 32;
    const float c2 = 0.09016844f;

    float m[4], lv[4];
#pragma unroll
    for (int j = 0; j < 4; ++j) { m[j] = -3.0e38f; lv[j] = 0.0f; }
    for (int j = 0; j < nch; ++j) {
        m[j]  = mlbuf[(size_t)(mlB + j) * 64 + q * 2];
        lv[j] = mlbuf[(size_t)(mlB + j) * 64 + q * 2 + 1];
    }
    float M = -3.0e38f;
    for (int j = 0; j < nch; ++j) M = fmaxf(M, m[j]);
    float a[4];
    float L = 0.0f;
    for (int j = 0; j < nch; ++j) {
        a[j] = __builtin_amdgcn_exp2f((m[j] - M) * c2);
        L += lv[j] * a[j];
    }
    const float inv = (L > 0.0f) ? 1.0f / L : 0.0f;

    u16* dst = attnb + ((size_t)(b * 2048 + c * 32 + q)) * 1024 + h * 256 + dp;
    float outv[32];
#pragma unroll
    for (int i = 0; i < 32; ++i) outv[i] = 0.0f;

    for (int j = 0; j < nch; ++j) {
        const float sc = a[j] * inv;
        const u16* src = (j < nch - 1)
            ? partO + (size_t)(slotB + j) * 8192 + q * 256 + dp
            : (const u16*)dst;                 // diag partial lives in attnb
#pragma unroll
        for (int w4 = 0; w4 < 4; ++w4) {
            const uint4 pk = *(const uint4*)(src + w4 * 8);
            const u32 ww[4] = { pk.x, pk.y, pk.z, pk.w };
#pragma unroll
            for (int e = 0; e < 4; ++e) {
                union { u32 u; float f; } lo, hi;
                lo.u = ww[e] << 16;
                hi.u = ww[e] & 0xffff0000u;
                outv[w4 * 8 + e * 2]     += sc * lo.f;
                outv[w4 * 8 + e * 2 + 1] += sc * hi.f;
            }
        }
    }
#pragma unroll
    for (int w4 = 0; w4 < 4; ++w4) {
        uint4 pk;
        pk.x = (u32)f2bf(outv[w4 * 8 + 0]) | ((u32)f2bf(outv[w4 * 8 + 1]) << 16);
        pk.y = (u32)f2bf(outv[w4 * 8 + 2]) | ((u32)f2bf(outv[w4 * 8 + 3]) << 16);
        pk.z = (u32)f2bf(outv[w4 * 8 + 4]) | ((u32)f2bf(outv[w4 * 8 + 5]) << 16);
        pk.w = (u32)f2bf(outv[w4 * 8 + 6]) | ((u32)f2bf(outv[w4 * 8 + 7]) << 16);
        *(uint4*)(dst + w4 * 8) = pk;
    }
}

extern "C" void kernel_launch(void* const* d_in, const int* in_sizes, int n_in,
                              void* d_out, int out_size, void* d_ws, size_t ws_size,
                              hipStream_t stream) {
    const float* x   = (const float*)d_in[0];
    const float* Wqk = (const float*)d_in[1];
    const float* bqk = (const float*)d_in[2];
    const float* Wv  = (const float*)d_in[3];
    const float* bv  = (const float*)d_in[4];
    const float* Wo  = (const float*)d_in[5];
    const float* bo  = (const float*)d_in[6];
    float* out = (float*)d_out;

    u16* ws    = (u16*)d_ws;
    u16* xb    = ws;             // 4194304 elems (dead after gemm1 -> partO overlay)
    u16* wqkb  = ws + 4194304;   // 1048576  (dead after gemm0)
    u16* wvb   = ws + 5242880;   // 1048576  (dead after gemm1)
    u16* wob   = ws + 6291456;   // 1048576  (live until gemm2)
    u16* kpack = ws + 7340032;   // 4194304
    u16* vpack = ws + 11534336;  // 4194304
    u16* attnb = ws + 15728640;  // 4194304
    u16* partO = ws;             // 768 slots x 8192 = 6291456 (= xb+wqkb+wvb exactly)
    float* mlbuf = (float*)d_out;  // d_out dead until gemm2: 1280 x 64 floats used

    cvt_kernel<<<7168, 256, 0, stream>>>(x, Wqk, Wv, Wo, ws);
    gemm_kernel<0><<<256, 256, 0, stream>>>(xb, wqkb, bqk, kpack);
    gemm_kernel<1><<<256, 256, 0, stream>>>(xb, wvb, bv, vpack);
    attn_kernel<<<1280, 64, 0, stream>>>(kpack, vpack, attnb, partO, mlbuf);
    combine_kernel<<<384, 256, 0, stream>>>(partO, mlbuf, attnb);
    gemm_kernel<2><<<256, 256, 0, stream>>>(attnb, wob, bo, out);
}

// Round 5
// 165.986 us; speedup vs baseline: 1.2368x; 1.2368x over previous
//
#include <hip/hip_runtime.h>
#include <cstdint>
#include <cstddef>

typedef unsigned short u16;
typedef uint32_t u32;
typedef __bf16 bf16x8 __attribute__((ext_vector_type(8)));
typedef float f32x4 __attribute__((ext_vector_type(4)));
typedef float f32x16 __attribute__((ext_vector_type(16)));

typedef __attribute__((address_space(1))) void gvoid;
typedef __attribute__((address_space(3))) void lvoid;

__device__ __forceinline__ void g2l16(const void* g, void* l) {
    __builtin_amdgcn_global_load_lds((gvoid*)g, (lvoid*)l, 16, 0, 0);
}

__device__ __forceinline__ u16 f2bf(float f) {
    union { float f; uint32_t u; } v;
    v.f = f;
    uint32_t r = (v.u + 0x7FFFu + ((v.u >> 16) & 1u)) >> 16;
    return (u16)r;
}

// ================= compressed-class problem tables (per batch: 24 problems) ==============
// p0: h0 (s=1, full causal). p1-3: h1 (s=3) g0..2. p4-10: h2 (s=7) g0..6. p11-23: h3 (s=13) g0..12.
// Q-list of problem (h,g) = class-g gather list; K near-window class A=(g-1024)%s, far-prefix class B=(g-3072)%s.
// valid key j for query m:  B-seg: j-m < cB ;  A-seg: cA <= j-m < dA.
__device__ const int T_h[24]  = {0, 1,1,1, 2,2,2,2,2,2,2, 3,3,3,3,3,3,3,3,3,3,3,3,3};
__device__ const int T_g[24]  = {0, 0,1,2, 0,1,2,3,4,5,6, 0,1,2,3,4,5,6,7,8,9,10,11,12};
__device__ const int T_qt[24] = {0, 64,86,108, 130,140,150,160,170,180,190,
                                 200,205,210,215,220,225,230,235,240,245,250,255,260};
__device__ const int T_LQ[24] = {2048, 683,683,682, 293,293,293,293,292,292,292,
                                 158,158,158,158,158,158,158,157,157,157,157,157,157};
__device__ const int T_ktB[24]= {0, 64,86,108, 140,150,160,170,180,190,130,
                                 245,250,255,260,200,205,210,215,220,225,230,235,240};
__device__ const int T_LkB[24]= {2048, 683,683,682, 293,293,293,292,292,292,293,
                                 157,157,157,157,158,158,158,158,158,158,158,157,157};
__device__ const int T_cB[24] = {1, -341,-341,-341, -146,-146,-146,-146,-146,-146,-145,
                                 -79,-79,-79,-79,-78,-78,-78,-78,-78,-78,-78,-78,-78};
__device__ const int T_ktA[24]= {0, 108,64,86, 180,190,130,140,150,160,170,
                                 215,220,225,230,235,240,245,250,255,260,200,205,210};
__device__ const int T_LkA[24]= {0, 682,683,683, 292,292,293,293,293,293,292,
                                 158,158,158,158,157,157,157,157,157,157,158,158,158};
__device__ const int T_cA[24] = {0, -342,-341,-341, -147,-147,-146,-146,-146,-146,-146,
                                 -79,-79,-79,-79,-79,-79,-79,-79,-79,-79,-78,-78,-78};
__device__ const int T_dA[24] = {0, 0,1,1, 0,0,1,1,1,1,1, 0,0,0,0,0,0,0,0,0,0,1,1,1};
__device__ const int T_nc[24] = {16, 6,6,6, 3,3,3,3,3,3,3, 2,2,2,2,2,2,2,2,2,2,2,2,2};
__device__ const int T_cht[24]= {72, 14,14,14, 5,5,5,5,5,5,5, 2,2,2,2,2,2,2,2,2,2,2,2,2};
__device__ const int T_ext[24]= {56, 8,8,8, 2,2,2,2,2,2,2, 0,0,0,0,0,0,0,0,0,0,0,0,0};
__device__ const int T_mcc[24]= {14, 4,4,4, 2,2,2,2,2,2,2, 0,0,0,0,0,0,0,0,0,0,0,0,0};
// grid sizes (host mirrors): attn 2*175=350, combine 2*40=80, zpad 2*23=46.

__device__ __forceinline__ void col_geom(int p, int c, int& ntB, int& tA0, int& nt) {
    const int LQ = T_LQ[p];
    const int Mc = c << 7;
    int mmax = Mc + 128; if (mmax > LQ) mmax = LQ; mmax -= 1;
    int jB = mmax + T_cB[p];
    if (jB < 0) jB = 0;
    if (jB > T_LkB[p]) jB = T_LkB[p];
    ntB = (jB + 31) >> 5;
    int jlo = Mc + T_cA[p]; if (jlo < 0) jlo = 0;
    int jhi = mmax + T_dA[p];
    if (jhi > T_LkA[p]) jhi = T_LkA[p];
    tA0 = jlo >> 5;
    int ntA = 0;
    if (jhi > jlo) ntA = ((jhi + 31) >> 5) - tA0;
    nt = ntB + ntA;
}

// ---------------- fp32 -> bf16 conversion of x, Wqk, Wv, Wo into ws ----------------
__global__ __launch_bounds__(256)
void cvt_kernel(const float* __restrict__ x, const float* __restrict__ wqk,
                const float* __restrict__ wv, const float* __restrict__ wo,
                u16* __restrict__ out) {
    int i = (blockIdx.x * 256 + threadIdx.x) * 4;
    const float* src;
    int off;
    if (i < 4194304)      { src = x;   off = 0; }
    else if (i < 5242880) { src = wqk; off = 4194304; }
    else if (i < 6291456) { src = wv;  off = 5242880; }
    else                  { src = wo;  off = 6291456; }
    float4 v = *(const float4*)(src + (i - off));
    ushort4 o;
    o.x = f2bf(v.x); o.y = f2bf(v.y); o.z = f2bf(v.z); o.w = f2bf(v.w);
    *(ushort4*)(out + i) = o;
}

// ---------------- zero V-pack pad keys (so PV mfma never multiplies P=0 by NaN) ----------
__global__ __launch_bounds__(256)
void zpad_kernel(u16* __restrict__ vpack) {
    const int ci = 1 + (blockIdx.x >> 1);
    const int b = blockIdx.x & 1;
    const int base = T_qt[ci];
    const int nxt = (ci < 23) ? T_qt[ci + 1] : 265;
    const int L = T_LQ[ci];
    const int npad = (nxt - base) * 32 - L;
    const int elems = npad << 8;
    for (int e = threadIdx.x; e < elems; e += 256) {
        const int j = L + (e >> 8);
        const int d = e & 255;
        const size_t addr = ((size_t)(b * 265 + base + (j >> 5))) * 8192
            + (size_t)(((j >> 4) & 1) * 8 + (d >> 5)) * 512
            + ((((j >> 3) & 1) * 32 + (d & 31)) * 8) + (j & 7);
        vpack[addr] = 0;
    }
}

// ---------------- fused QK+V projection GEMM, epilogue packs class lists ----------------
// BM=128 BN=128 BK=32, dbuf, 4 waves. bid map: m-panel = bid&31 (XCD-local A), n-panel = bid>>5.
__global__ __launch_bounds__(256)
void gemm_qkv(const u16* __restrict__ A, const u16* __restrict__ Bq, const u16* __restrict__ Bv,
              const float* __restrict__ bq, const float* __restrict__ bv,
              u16* __restrict__ kpack, u16* __restrict__ vpack) {
    __shared__ __align__(16) u16 As[2][4096], Bqs[2][4096], Bvs[2][4096];
    const int bid = blockIdx.x;
    const int m0 = (bid & 31) * 128;
    const int n0 = (bid >> 5) * 128;
    const int t = threadIdx.x;
    const int lane = t & 63;
    const int wid = t >> 6;
    const int wr = wid >> 1, wc = wid & 1;
    const int l15 = lane & 15, l4 = lane >> 4;

    f32x4 aq[4][4] = {}, av[4][4] = {};

    auto stage = [&](int buf, int kt) {
        const int kbase = kt * 32;
#pragma unroll
        for (int c2 = 0; c2 < 2; ++c2) {
            const int pp = c2 * 4096 + t * 16;
            const int row = pp >> 6;
            const int koff = (pp & 63) >> 1;
            g2l16(A  + (size_t)(m0 + row) * 1024 + kbase + koff, (char*)As[buf] + pp);
            g2l16(Bq + (size_t)(n0 + row) * 1024 + kbase + koff, (char*)Bqs[buf] + pp);
            g2l16(Bv + (size_t)(n0 + row) * 1024 + kbase + koff, (char*)Bvs[buf] + pp);
        }
    };

    stage(0, 0);
    asm volatile("s_waitcnt vmcnt(0)" ::: "memory");
    __syncthreads();

    int cur = 0;
    for (int kt = 0; kt < 32; ++kt) {
        if (kt + 1 < 32) stage(cur ^ 1, kt + 1);
        bf16x8 af[4], bfq[4], bfv[4];
#pragma unroll
        for (int mi = 0; mi < 4; ++mi)
            af[mi] = *(const bf16x8*)((const char*)As[cur] + (wr * 64 + mi * 16 + l15) * 64 + l4 * 16);
#pragma unroll
        for (int ni = 0; ni < 4; ++ni) {
            bfq[ni] = *(const bf16x8*)((const char*)Bqs[cur] + (wc * 64 + ni * 16 + l15) * 64 + l4 * 16);
            bfv[ni] = *(const bf16x8*)((const char*)Bvs[cur] + (wc * 64 + ni * 16 + l15) * 64 + l4 * 16);
        }
#pragma unroll
        for (int mi = 0; mi < 4; ++mi)
#pragma unroll
            for (int ni = 0; ni < 4; ++ni) {
                aq[mi][ni] = __builtin_amdgcn_mfma_f32_16x16x32_bf16(af[mi], bfq[ni], aq[mi][ni], 0, 0, 0);
                av[mi][ni] = __builtin_amdgcn_mfma_f32_16x16x32_bf16(af[mi], bfv[ni], av[mi][ni], 0, 0, 0);
            }
        asm volatile("s_waitcnt vmcnt(0)" ::: "memory");
        __syncthreads();
        cur ^= 1;
    }

    // ---- epilogue: pack into class lists ----
    const int mbase = m0 + wr * 64 + l4 * 4;
    const int nbase = n0 + wc * 64 + l15;
    const int b_ = m0 >> 11;
    const size_t PB = (size_t)b_ * 265 * 8192;
    const int h = n0 >> 8;                       // constant per block
    const int cb0 = (h == 0) ? 0 : (h == 1) ? 64 : (h == 2) ? 130 : 200;
    const int cbs = (h == 0) ? 0 : (h == 1) ? 22 : (h == 2) ? 10 : 5;

    int jr[16], tb_[16];
#pragma unroll
    for (int mi = 0; mi < 4; ++mi)
#pragma unroll
        for (int r = 0; r < 4; ++r) {
            const int i = (mbase + mi * 16 + r) & 2047;
            int cls, j;
            if (h == 0)      { cls = 0;      j = i;      }
            else if (h == 1) { cls = i % 3;  j = i / 3;  }
            else if (h == 2) { cls = i % 7;  j = i / 7;  }
            else             { cls = i % 13; j = i / 13; }
            jr[mi * 4 + r] = j;
            tb_[mi * 4 + r] = cb0 + cbs * cls + (j >> 5);
        }

#pragma unroll
    for (int ni = 0; ni < 4; ++ni) {
        const int n = nbase + ni * 16;
        const int d = n & 255;
        const float bq_ = bq[n];
        const float bv_ = bv[n];
#pragma unroll
        for (int mi = 0; mi < 4; ++mi)
#pragma unroll
            for (int r = 0; r < 4; ++r) {
                const int idx = mi * 4 + r;
                const int j = jr[idx];
                const size_t tb = PB + (size_t)tb_[idx] * 8192;
                kpack[tb + (d >> 4) * 512 + (((d >> 3) & 1) * 32 + (j & 31)) * 8 + (d & 7)]
                    = f2bf(aq[mi][ni][r] + bq_);
                vpack[tb + (((j >> 4) & 1) * 8 + (d >> 5)) * 512 + (((j >> 3) & 1) * 32 + (d & 31)) * 8 + (j & 7)]
                    = f2bf(av[mi][ni][r] + bv_);
            }
    }
}

// ---------------- compressed flash attention ----------------
// Block = 4 waves, Q-tile 128 (wave w owns 32 compressed queries), shared 32-key LDS tile
// (K 16KB + V 16KB) double-buffered (64KB). Virtual tile list = B-prefix tiles + A-window tiles.
__global__ __launch_bounds__(256)
void attn_kernel(const u16* __restrict__ kpack, const u16* __restrict__ vpack,
                 u16* __restrict__ attnb, u16* __restrict__ partO, float* __restrict__ mlbuf) {
    __shared__ __align__(16) unsigned char sm[65536];

    // ---- block descriptor scan ----
    const int b = blockIdx.x & 1;
    int rb = blockIdx.x >> 1;
    int colg = 0, exb = 0, p = 0;
    for (; p < 24; ++p) {
        if (rb >= T_cht[p]) { rb -= T_cht[p]; colg += T_nc[p]; exb += T_ext[p]; }
        else break;
    }
    int col = 0, chunk = 0, ntB = 0, tA0 = 0, nt = 0;
    for (int c = T_nc[p] - 1; c >= 0; --c) {
        int nb, ta, n;
        col_geom(p, c, nb, ta, n);
        const int nch2 = (n + 7) >> 3;
        if (rb < nch2) { col = c; chunk = rb; ntB = nb; tA0 = ta; nt = n; break; }
        rb -= nch2; ++colg; exb += nch2 - 1;
    }
    const int nch = (nt + 7) >> 3;
    const int h = T_h[p], g = T_g[p];
    const int s = (h == 0) ? 1 : (h == 1) ? 3 : (h == 2) ? 7 : 13;
    const int LQ = T_LQ[p];
    const int cB = T_cB[p], cA = T_cA[p], dA = T_dA[p];
    const int ktB = T_ktB[p], ktA = T_ktA[p];
    const int PBi = b * 265;

    const int t = threadIdx.x;
    const int w = t >> 6;
    const int l = t & 63;
    const int l31 = l & 31, h5 = l >> 5;
    const int m = (col << 7) + (w << 5) + l31;     // compressed query index
    const int mq = (m < LQ) ? m : (LQ - 1);        // clamp for loads
    const float c2 = 0.09016844f;                  // (1/16) * log2(e)

    // Q fragments from kpack (class-g list)
    bf16x8 qf[16];
    {
        const u16* qb = kpack + ((size_t)(PBi + T_qt[p] + (mq >> 5))) * 8192
                        + (size_t)(h5 * 32 + (mq & 31)) * 8;
#pragma unroll
        for (int dc = 0; dc < 16; ++dc)
            qf[dc] = *(const bf16x8*)(qb + dc * 512);
    }

    auto vtile = [&](int tv) -> int {
        return (tv < ntB) ? (ktB + tv) : (ktA + tA0 + (tv - ntB));
    };
    auto stage = [&](int tile, int buf) {
        const size_t kb = ((size_t)(PBi + tile)) * 8192;
        unsigned char* Kd = sm + buf * 32768;
        unsigned char* Vd = Kd + 16384;
#pragma unroll
        for (int i2 = 0; i2 < 4; ++i2) {
            const int off = i2 * 4096 + t * 16;
            g2l16(kpack + kb + (off >> 1), Kd + off);
            g2l16(vpack + kb + (off >> 1), Vd + off);
        }
    };

    const int tt0 = chunk * 8;
    int tt1 = tt0 + 8; if (tt1 > nt) tt1 = nt;

    f32x16 o[8] = {};
    float mrun = -3.0e38f, lrun = 0.0f;

    stage(vtile(tt0), 0);
    asm volatile("s_waitcnt vmcnt(0)" ::: "memory");
    __syncthreads();

    int buf = 0;
    for (int tv = tt0; tv < tt1; ++tv) {
        if (tv + 1 < tt1) stage(vtile(tv + 1), buf ^ 1);

        int j0, lo, hi;
        if (tv < ntB) { j0 = tv << 5; lo = -100000; hi = cB; }
        else { const int ta = tA0 + tv - ntB; j0 = ta << 5; lo = cA; hi = dA; }

        const unsigned char* Kb = sm + buf * 32768;
        const unsigned char* Vb = Kb + 16384;
        const int lslot = (h5 * 32 + l31) * 16;

        // S^T = K * Q^T
        f32x16 sacc = {};
#pragma unroll
        for (int dc = 0; dc < 16; ++dc) {
            const bf16x8 kf = *(const bf16x8*)(Kb + dc * 1024 + lslot);
            sacc = __builtin_amdgcn_mfma_f32_32x32x16_bf16(kf, qf[dc], sacc, 0, 0, 0);
        }

        // mask + online softmax (lane-local state; e = j - m)
        const int ebase = j0 - m;
        float sv[16];
        float tmax = -3.0e38f;
#pragma unroll
        for (int r = 0; r < 16; ++r) {
            const int km = (r & 3) + 8 * (r >> 2) + 4 * h5;
            const int e = ebase + km;
            const bool ok = (e >= lo) && (e < hi);
            sv[r] = ok ? sacc[r] : -3.0e38f;
            tmax = fmaxf(tmax, sv[r]);
        }
        tmax = fmaxf(tmax, __shfl_xor(tmax, 32, 64));
        if (!__all(tmax <= mrun + 8.0f)) {     // defer-max
            const float mnew = fmaxf(mrun, tmax);
            const float fsc = __builtin_amdgcn_exp2f((mrun - mnew) * c2);
            lrun *= fsc;
#pragma unroll
            for (int ch = 0; ch < 8; ++ch)
#pragma unroll
                for (int r = 0; r < 16; ++r)
                    o[ch][r] *= fsc;
            mrun = mnew;
        }
        float psum = 0.0f;
#pragma unroll
        for (int r = 0; r < 16; ++r) {
            const float pv = (sv[r] > -1.0e37f) ? __builtin_amdgcn_exp2f((sv[r] - mrun) * c2) : 0.0f;
            sv[r] = pv;
            psum += pv;
        }
        lrun += psum;

        // P -> bf16 fragments: cvt_pk + permlane32_swap
        uint32_t w0, w1, w2, w3, w4, w5, w6, w7;
        asm("v_cvt_pk_bf16_f32 %0,%1,%2" : "=v"(w0) : "v"(sv[0]),  "v"(sv[1]));
        asm("v_cvt_pk_bf16_f32 %0,%1,%2" : "=v"(w1) : "v"(sv[2]),  "v"(sv[3]));
        asm("v_cvt_pk_bf16_f32 %0,%1,%2" : "=v"(w2) : "v"(sv[4]),  "v"(sv[5]));
        asm("v_cvt_pk_bf16_f32 %0,%1,%2" : "=v"(w3) : "v"(sv[6]),  "v"(sv[7]));
        asm("v_cvt_pk_bf16_f32 %0,%1,%2" : "=v"(w4) : "v"(sv[8]),  "v"(sv[9]));
        asm("v_cvt_pk_bf16_f32 %0,%1,%2" : "=v"(w5) : "v"(sv[10]), "v"(sv[11]));
        asm("v_cvt_pk_bf16_f32 %0,%1,%2" : "=v"(w6) : "v"(sv[12]), "v"(sv[13]));
        asm("v_cvt_pk_bf16_f32 %0,%1,%2" : "=v"(w7) : "v"(sv[14]), "v"(sv[15]));
        asm("v_permlane32_swap_b32 %0, %1" : "+v"(w0), "+v"(w2));
        asm("v_permlane32_swap_b32 %0, %1" : "+v"(w1), "+v"(w3));
        asm("v_permlane32_swap_b32 %0, %1" : "+v"(w4), "+v"(w6));
        asm("v_permlane32_swap_b32 %0, %1" : "+v"(w5), "+v"(w7));
        union { uint32_t u[4]; bf16x8 v; } p0u, p1u;
        p0u.u[0] = w0; p0u.u[1] = w1; p0u.u[2] = w2; p0u.u[3] = w3;
        p1u.u[0] = w4; p1u.u[1] = w5; p1u.u[2] = w6; p1u.u[3] = w7;

        // O^T += V^T * P^T
#pragma unroll
        for (int kk = 0; kk < 2; ++kk) {
            const bf16x8 pf = kk ? p1u.v : p0u.v;
#pragma unroll
            for (int ch = 0; ch < 8; ++ch) {
                const bf16x8 vf = *(const bf16x8*)(Vb + (kk * 8 + ch) * 1024 + lslot);
                o[ch] = __builtin_amdgcn_mfma_f32_32x32x16_bf16(vf, pf, o[ch], 0, 0, 0);
            }
        }

        asm volatile("s_waitcnt vmcnt(0)" ::: "memory");
        __syncthreads();
        buf ^= 1;
    }

    lrun += __shfl_xor(lrun, 32, 64);

    float scale = 1.0f;
    u16* ab;
    const int qm = (w << 5) + l31;                 // 0..127 within tile
    if (nch == 1) {
        scale = (lrun > 0.0f) ? 1.0f / lrun : 0.0f;
        ab = attnb + ((size_t)(b * 2048 + g + m * s)) * 1024 + h * 256;
    } else {
        if (h5 == 0 && m < LQ) {
            const int colid = b * 81 + colg;
            mlbuf[(size_t)((colid * 8 + chunk) * 256) + qm * 2]     = mrun;
            mlbuf[(size_t)((colid * 8 + chunk) * 256) + qm * 2 + 1] = lrun;
        }
        if (chunk == 0)
            ab = attnb + ((size_t)(b * 2048 + g + m * s)) * 1024 + h * 256;
        else
            ab = partO + (size_t)(b * 94 + exb + chunk - 1) * 32768 + (size_t)qm * 256;
    }

    if (m < LQ) {
#pragma unroll
        for (int ch = 0; ch < 8; ++ch) {
#pragma unroll
            for (int g2 = 0; g2 < 4; ++g2) {
                ushort4 wv4;
                wv4.x = f2bf(o[ch][g2 * 4 + 0] * scale);
                wv4.y = f2bf(o[ch][g2 * 4 + 1] * scale);
                wv4.z = f2bf(o[ch][g2 * 4 + 2] * scale);
                wv4.w = f2bf(o[ch][g2 * 4 + 3] * scale);
                *(ushort4*)(ab + ch * 32 + 8 * g2 + 4 * h5) = wv4;
            }
        }
    }
}

// ---------------- combine chunked columns ----------------
__global__ __launch_bounds__(256)
void combine_kernel(const u16* __restrict__ partO, const float* __restrict__ mlbuf,
                    u16* __restrict__ attnb) {
    const int b = blockIdx.x & 1;
    int rb = blockIdx.x >> 1;
    int colg = 0, exb = 0, p = 0;
    for (; p < 24; ++p) {
        if (rb >= T_mcc[p]) { rb -= T_mcc[p]; colg += T_nc[p]; exb += T_ext[p]; }
        else break;
    }
    int col = 0, nch = 0;
    for (int c = T_nc[p] - 1; c >= 0; --c) {
        int nb, ta, n;
        col_geom(p, c, nb, ta, n);
        const int nc2 = (n + 7) >> 3;
        if (nc2 > 1) {
            if (rb == 0) { col = c; nch = nc2; break; }
            --rb;
        }
        ++colg; exb += nc2 - 1;
    }
    const int h = T_h[p], g = T_g[p];
    const int s = (h == 0) ? 1 : (h == 1) ? 3 : (h == 2) ? 7 : 13;
    const int LQ = T_LQ[p];
    const int colid = b * 81 + colg;
    const float c2 = 0.09016844f;

    const int t = threadIdx.x;
    const int q = t >> 1, dpart = (t & 1) * 128;
    const int m = (col << 7) + q;

    float mj[8], lj[8];
#pragma unroll
    for (int j5 = 0; j5 < 8; ++j5) {
        if (j5 < nch) {
            mj[j5] = mlbuf[(size_t)((colid * 8 + j5) * 256) + q * 2];
            lj[j5] = mlbuf[(size_t)((colid * 8 + j5) * 256) + q * 2 + 1];
        } else { mj[j5] = -3.0e38f; lj[j5] = 0.0f; }
    }
    float M = -3.0e38f;
#pragma unroll
    for (int j5 = 0; j5 < 8; ++j5) if (j5 < nch) M = fmaxf(M, mj[j5]);
    float L = 0.0f, al[8];
#pragma unroll
    for (int j5 = 0; j5 < 8; ++j5) {
        al[j5] = (j5 < nch) ? __builtin_amdgcn_exp2f((mj[j5] - M) * c2) : 0.0f;
        L += lj[j5] * al[j5];
    }
    const float inv = (L > 0.0f) ? 1.0f / L : 0.0f;
#pragma unroll
    for (int j5 = 0; j5 < 8; ++j5) al[j5] *= inv;

    u16* dst = attnb + ((size_t)(b * 2048 + g + m * s)) * 1024 + h * 256 + dpart;

    for (int ss = 0; ss < 4; ++ss) {
        float acc32[32];
#pragma unroll
        for (int e = 0; e < 32; ++e) acc32[e] = 0.0f;
#pragma unroll
        for (int j5 = 0; j5 < 8; ++j5) {
            if (j5 >= nch) continue;
            const u16* src = (j5 == 0)
                ? (dst + ss * 32)
                : (partO + (size_t)(b * 94 + exb + j5 - 1) * 32768 + (size_t)q * 256 + dpart + ss * 32);
            const float sc = al[j5];
#pragma unroll
            for (int w4 = 0; w4 < 4; ++w4) {
                const uint4 pk = *(const uint4*)(src + w4 * 8);
                const u32 ww[4] = { pk.x, pk.y, pk.z, pk.w };
#pragma unroll
                for (int e = 0; e < 4; ++e) {
                    union { u32 u; float f; } lo2, hi2;
                    lo2.u = ww[e] << 16;
                    hi2.u = ww[e] & 0xffff0000u;
                    acc32[w4 * 8 + e * 2]     += sc * lo2.f;
                    acc32[w4 * 8 + e * 2 + 1] += sc * hi2.f;
                }
            }
        }
        if (m < LQ) {
#pragma unroll
            for (int w4 = 0; w4 < 4; ++w4) {
                uint4 pk;
                pk.x = (u32)f2bf(acc32[w4 * 8 + 0]) | ((u32)f2bf(acc32[w4 * 8 + 1]) << 16);
                pk.y = (u32)f2bf(acc32[w4 * 8 + 2]) | ((u32)f2bf(acc32[w4 * 8 + 3]) << 16);
                pk.z = (u32)f2bf(acc32[w4 * 8 + 4]) | ((u32)f2bf(acc32[w4 * 8 + 5]) << 16);
                pk.w = (u32)f2bf(acc32[w4 * 8 + 6]) | ((u32)f2bf(acc32[w4 * 8 + 7]) << 16);
                *(uint4*)(dst + ss * 32 + w4 * 8) = pk;
            }
        }
    }
}

// ---------------- output GEMM: out = attnb @ Wo^T + bo (f32) ----------------
__global__ __launch_bounds__(256)
void gemm_out(const u16* __restrict__ A, const u16* __restrict__ Bw,
              const float* __restrict__ bias, float* __restrict__ outp) {
    __shared__ __align__(16) u16 As[2][4096], Bs[2][4096];
    const int bid = blockIdx.x;
    const int m0 = (bid & 31) * 128;
    const int n0 = (bid >> 5) * 128;
    const int t = threadIdx.x;
    const int lane = t & 63;
    const int wid = t >> 6;
    const int wr = wid >> 1, wc = wid & 1;
    const int l15 = lane & 15, l4 = lane >> 4;

    f32x4 acc[4][4] = {};

    auto stage = [&](int buf, int kt) {
        const int kbase = kt * 32;
#pragma unroll
        for (int c2 = 0; c2 < 2; ++c2) {
            const int pp = c2 * 4096 + t * 16;
            const int row = pp >> 6;
            const int koff = (pp & 63) >> 1;
            g2l16(A  + (size_t)(m0 + row) * 1024 + kbase + koff, (char*)As[buf] + pp);
            g2l16(Bw + (size_t)(n0 + row) * 1024 + kbase + koff, (char*)Bs[buf] + pp);
        }
    };

    stage(0, 0);
    asm volatile("s_waitcnt vmcnt(0)" ::: "memory");
    __syncthreads();

    int cur = 0;
    for (int kt = 0; kt < 32; ++kt) {
        if (kt + 1 < 32) stage(cur ^ 1, kt + 1);
        bf16x8 af[4], bfr[4];
#pragma unroll
        for (int mi = 0; mi < 4; ++mi)
            af[mi] = *(const bf16x8*)((const char*)As[cur] + (wr * 64 + mi * 16 + l15) * 64 + l4 * 16);
#pragma unroll
        for (int ni = 0; ni < 4; ++ni)
            bfr[ni] = *(const bf16x8*)((const char*)Bs[cur] + (wc * 64 + ni * 16 + l15) * 64 + l4 * 16);
#pragma unroll
        for (int mi = 0; mi < 4; ++mi)
#pragma unroll
            for (int ni = 0; ni < 4; ++ni)
                acc[mi][ni] = __builtin_amdgcn_mfma_f32_16x16x32_bf16(af[mi], bfr[ni], acc[mi][ni], 0, 0, 0);
        asm volatile("s_waitcnt vmcnt(0)" ::: "memory");
        __syncthreads();
        cur ^= 1;
    }

    const int mbase = m0 + wr * 64 + l4 * 4;
    const int nbase = n0 + wc * 64 + l15;
#pragma unroll
    for (int ni = 0; ni < 4; ++ni) {
        const int n = nbase + ni * 16;
        const float bv = bias[n];
#pragma unroll
        for (int mi = 0; mi < 4; ++mi) {
            const int mrow = mbase + mi * 16;
#pragma unroll
            for (int r = 0; r < 4; ++r)
                outp[(size_t)(mrow + r) * 1024 + n] = acc[mi][ni][r] + bv;
        }
    }
}

extern "C" void kernel_launch(void* const* d_in, const int* in_sizes, int n_in,
                              void* d_out, int out_size, void* d_ws, size_t ws_size,
                              hipStream_t stream) {
    const float* x   = (const float*)d_in[0];
    const float* Wqk = (const float*)d_in[1];
    const float* bqk = (const float*)d_in[2];
    const float* Wv  = (const float*)d_in[3];
    const float* bv  = (const float*)d_in[4];
    const float* Wo  = (const float*)d_in[5];
    const float* bo  = (const float*)d_in[6];
    float* out = (float*)d_out;

    u16* ws    = (u16*)d_ws;
    u16* xb    = ws;             // 4194304
    u16* wqkb  = ws + 4194304;   // 1048576
    u16* wvb   = ws + 5242880;   // 1048576
    u16* wob   = ws + 6291456;   // 1048576
    u16* kpack = ws + 7340032;   // 2*265*8192 = 4341760
    u16* vpack = ws + 11681792;  // 4341760
    u16* attnb = ws + 16023552;  // 4194304  (end 20217856 u16 = 38.6 MiB)
    u16* partO = ws;             // overlays xb/wqkb/wvb (dead after gemm_qkv): 188*32768 = 6160384
    float* mlbuf = (float*)d_out; // d_out dead until gemm_out; 331776 floats used

    cvt_kernel<<<7168, 256, 0, stream>>>(x, Wqk, Wv, Wo, ws);
    zpad_kernel<<<46, 256, 0, stream>>>(vpack);
    gemm_qkv<<<256, 256, 0, stream>>>(xb, wqkb, wvb, bqk, bv, kpack, vpack);
    attn_kernel<<<350, 256, 0, stream>>>(kpack, vpack, attnb, partO, mlbuf);
    combine_kernel<<<80, 256, 0, stream>>>(partO, mlbuf, attnb);
    gemm_out<<<256, 256, 0, stream>>>(attnb, wob, bo, out);
}

// Round 6
// 149.020 us; speedup vs baseline: 1.3776x; 1.1138x over previous
//
#include <hip/hip_runtime.h>
#include <cstdint>
#include <cstddef>

typedef unsigned short u16;
typedef uint32_t u32;
typedef __bf16 bf16x8 __attribute__((ext_vector_type(8)));
typedef float f32x4 __attribute__((ext_vector_type(4)));
typedef float f32x16 __attribute__((ext_vector_type(16)));

typedef __attribute__((address_space(1))) void gvoid;
typedef __attribute__((address_space(3))) void lvoid;

__device__ __forceinline__ void g2l16(const void* g, void* l) {
    __builtin_amdgcn_global_load_lds((gvoid*)g, (lvoid*)l, 16, 0, 0);
}

__device__ __forceinline__ u16 f2bf(float f) {
    union { float f; uint32_t u; } v;
    v.f = f;
    uint32_t r = (v.u + 0x7FFFu + ((v.u >> 16) & 1u)) >> 16;
    return (u16)r;
}

// ================= compressed-class problem tables (per batch: 24 problems) ==============
__device__ const int T_h[24]  = {0, 1,1,1, 2,2,2,2,2,2,2, 3,3,3,3,3,3,3,3,3,3,3,3,3};
__device__ const int T_g[24]  = {0, 0,1,2, 0,1,2,3,4,5,6, 0,1,2,3,4,5,6,7,8,9,10,11,12};
__device__ const int T_LQ[24] = {2048, 683,683,682, 293,293,293,293,292,292,292,
                                 158,158,158,158,158,158,158,157,157,157,157,157,157};
__device__ const int T_ktB[24]= {0, 64,86,108, 140,150,160,170,180,190,130,
                                 245,250,255,260,200,205,210,215,220,225,230,235,240};
__device__ const int T_LkB[24]= {2048, 683,683,682, 293,293,293,292,292,292,293,
                                 157,157,157,157,158,158,158,158,158,158,158,157,157};
__device__ const int T_cB[24] = {1, -341,-341,-341, -146,-146,-146,-146,-146,-146,-145,
                                 -79,-79,-79,-79,-78,-78,-78,-78,-78,-78,-78,-78,-78};
__device__ const int T_ktA[24]= {0, 108,64,86, 180,190,130,140,150,160,170,
                                 215,220,225,230,235,240,245,250,255,260,200,205,210};
__device__ const int T_LkA[24]= {0, 682,683,683, 292,292,293,293,293,293,292,
                                 158,158,158,158,157,157,157,157,157,157,158,158,158};
__device__ const int T_cA[24] = {0, -342,-341,-341, -147,-147,-146,-146,-146,-146,-146,
                                 -79,-79,-79,-79,-79,-79,-79,-79,-79,-79,-78,-78,-78};
__device__ const int T_dA[24] = {0, 0,1,1, 0,0,1,1,1,1,1, 0,0,0,0,0,0,0,0,0,0,1,1,1};
__device__ const int T_nc[24] = {16, 6,6,6, 3,3,3,3,3,3,3, 2,2,2,2,2,2,2,2,2,2,2,2,2};
__device__ const int T_cht[24]= {72, 14,14,14, 5,5,5,5,5,5,5, 2,2,2,2,2,2,2,2,2,2,2,2,2};
__device__ const int T_ext[24]= {56, 8,8,8, 2,2,2,2,2,2,2, 0,0,0,0,0,0,0,0,0,0,0,0,0};
__device__ const int T_mcc[24]= {14, 4,4,4, 2,2,2,2,2,2,2, 0,0,0,0,0,0,0,0,0,0,0,0,0};

__device__ __forceinline__ void col_geom(int p, int c, int& ntB, int& tA0, int& nt) {
    const int LQ = T_LQ[p];
    const int Mc = c << 7;
    int mmax = Mc + 128; if (mmax > LQ) mmax = LQ; mmax -= 1;
    int jB = mmax + T_cB[p];
    if (jB < 0) jB = 0;
    if (jB > T_LkB[p]) jB = T_LkB[p];
    ntB = (jB + 31) >> 5;
    int jlo = Mc + T_cA[p]; if (jlo < 0) jlo = 0;
    int jhi = mmax + T_dA[p];
    if (jhi > T_LkA[p]) jhi = T_LkA[p];
    tA0 = jlo >> 5;
    int ntA = 0;
    if (jhi > jlo) ntA = ((jhi + 31) >> 5) - tA0;
    nt = ntB + ntA;
}

__device__ __forceinline__ u16* partO_addr(u16* lo, u16* hi, int slot) {
    return (slot < 128) ? (lo + (size_t)slot * 32768) : (hi + (size_t)(slot - 128) * 32768);
}
__device__ __forceinline__ const u16* partO_addr_c(const u16* lo, const u16* hi, int slot) {
    return (slot < 128) ? (lo + (size_t)slot * 32768) : (hi + (size_t)(slot - 128) * 32768);
}

// ---------------- fp32 -> bf16 conversion of x, Wqk, Wv, Wo into ws ----------------
__global__ __launch_bounds__(256)
void cvt_kernel(const float* __restrict__ x, const float* __restrict__ wqk,
                const float* __restrict__ wv, const float* __restrict__ wo,
                u16* __restrict__ out) {
    int i = (blockIdx.x * 256 + threadIdx.x) * 4;
    const float* src;
    int off;
    if (i < 4194304)      { src = x;   off = 0; }
    else if (i < 5242880) { src = wqk; off = 4194304; }
    else if (i < 6291456) { src = wv;  off = 5242880; }
    else                  { src = wo;  off = 6291456; }
    float4 v = *(const float4*)(src + (i - off));
    ushort4 o;
    o.x = f2bf(v.x); o.y = f2bf(v.y); o.z = f2bf(v.z); o.w = f2bf(v.w);
    *(ushort4*)(out + i) = o;
}

// ---------------- fused QK+V projection GEMM, row-major bf16 outputs ----------------
// BM=128 BN=64 BK=32, double-buffered, 4 waves (2x2), grid 512 (32 m x 16 n).
__global__ __launch_bounds__(256)
void gemm_qkv(const u16* __restrict__ A, const u16* __restrict__ Bq, const u16* __restrict__ Bv,
              const float* __restrict__ bq, const float* __restrict__ bv,
              u16* __restrict__ qkb, u16* __restrict__ vb) {
    __shared__ __align__(16) u16 As[2][4096], Bqs[2][2048], Bvs[2][2048];
    const int bid = blockIdx.x;
    const int m0 = (bid >> 4) * 128;
    const int n0 = (bid & 15) * 64;
    const int t = threadIdx.x;
    const int lane = t & 63;
    const int wid = t >> 6;
    const int wr = wid >> 1, wc = wid & 1;
    const int l15 = lane & 15, l4 = lane >> 4;

    f32x4 aq[4][2] = {}, av[4][2] = {};

    auto stage = [&](int buf, int kt) {
        const int kbase = kt * 32;
#pragma unroll
        for (int c2 = 0; c2 < 2; ++c2) {
            const int pp = c2 * 4096 + t * 16;
            g2l16(A + (size_t)(m0 + (pp >> 6)) * 1024 + kbase + ((pp & 63) >> 1), (char*)As[buf] + pp);
        }
        const int pb = t * 16;
        const int rb = pb >> 6, kb = (pb & 63) >> 1;
        g2l16(Bq + (size_t)(n0 + rb) * 1024 + kbase + kb, (char*)Bqs[buf] + pb);
        g2l16(Bv + (size_t)(n0 + rb) * 1024 + kbase + kb, (char*)Bvs[buf] + pb);
    };

    stage(0, 0);
    asm volatile("s_waitcnt vmcnt(0)" ::: "memory");
    __syncthreads();

    int cur = 0;
    for (int kt = 0; kt < 32; ++kt) {
        if (kt + 1 < 32) stage(cur ^ 1, kt + 1);
        bf16x8 af[4], bfq[2], bfv[2];
#pragma unroll
        for (int mi = 0; mi < 4; ++mi)
            af[mi] = *(const bf16x8*)((const char*)As[cur] + (wr * 64 + mi * 16 + l15) * 64 + l4 * 16);
#pragma unroll
        for (int ni = 0; ni < 2; ++ni) {
            bfq[ni] = *(const bf16x8*)((const char*)Bqs[cur] + (wc * 32 + ni * 16 + l15) * 64 + l4 * 16);
            bfv[ni] = *(const bf16x8*)((const char*)Bvs[cur] + (wc * 32 + ni * 16 + l15) * 64 + l4 * 16);
        }
#pragma unroll
        for (int mi = 0; mi < 4; ++mi)
#pragma unroll
            for (int ni = 0; ni < 2; ++ni) {
                aq[mi][ni] = __builtin_amdgcn_mfma_f32_16x16x32_bf16(af[mi], bfq[ni], aq[mi][ni], 0, 0, 0);
                av[mi][ni] = __builtin_amdgcn_mfma_f32_16x16x32_bf16(af[mi], bfv[ni], av[mi][ni], 0, 0, 0);
            }
        asm volatile("s_waitcnt vmcnt(0)" ::: "memory");
        __syncthreads();
        cur ^= 1;
    }

    const int mbase = m0 + wr * 64 + l4 * 4;
    const int nbase = n0 + wc * 32 + l15;
#pragma unroll
    for (int ni = 0; ni < 2; ++ni) {
        const int n = nbase + ni * 16;
        const float bq_ = bq[n];
        const float bv_ = bv[n];
#pragma unroll
        for (int mi = 0; mi < 4; ++mi) {
            const int mrow = mbase + mi * 16;
#pragma unroll
            for (int r = 0; r < 4; ++r) {
                qkb[(size_t)(mrow + r) * 1024 + n] = f2bf(aq[mi][ni][r] + bq_);
                vb [(size_t)(mrow + r) * 1024 + n] = f2bf(av[mi][ni][r] + bv_);
            }
        }
    }
}

// ---------------- repack V into fragment-major class-tile layout ----------------
// Grid 530 = 2 batches x 265 tiles. Stage 32 gathered V rows (XOR-swizzled) -> LDS,
// zero pads, write vpack tile fully coalesced (16B/lane).
__global__ __launch_bounds__(256)
void repack_v(const u16* __restrict__ vb, u16* __restrict__ vpack) {
    __shared__ __align__(16) unsigned char sm[16384];
    const int bid = blockIdx.x;
    const int b = bid & 1;
    const int tt = bid >> 1;
    int h, cls, jt, LK;
    if (tt < 64)       { h = 0; cls = 0;               jt = tt;            LK = 2048; }
    else if (tt < 130) { h = 1; cls = (tt - 64) / 22;  jt = (tt - 64) % 22;  LK = (cls < 2) ? 683 : 682; }
    else if (tt < 200) { h = 2; cls = (tt - 130) / 10; jt = (tt - 130) % 10; LK = (cls < 4) ? 293 : 292; }
    else               { h = 3; cls = (tt - 200) / 5;  jt = (tt - 200) % 5;  LK = (cls < 7) ? 158 : 157; }
    const int s = (h == 0) ? 1 : (h == 1) ? 3 : (h == 2) ? 7 : 13;
    const int j0 = jt * 32;
    int nval = LK - j0; if (nval > 32) nval = 32;
    const int t = threadIdx.x;

#pragma unroll
    for (int i2 = 0; i2 < 4; ++i2) {
        const int p = i2 * 4096 + t * 16;
        const int j = p >> 9;
        const int cb = (p & 511) ^ ((j & 31) << 4);
        const int jj = (j < nval) ? j : (nval - 1);
        const int tok = cls + (j0 + jj) * s;
        g2l16(vb + (size_t)((b * 2048 + tok) * 1024 + h * 256) + (cb >> 1), sm + p);
    }
    asm volatile("s_waitcnt vmcnt(0)" ::: "memory");
    __syncthreads();
    if (nval < 32) {
        const int pb = nval * 512;
        for (int off = pb + t * 16; off < 16384; off += 4096) {
            uint4 z; z.x = 0; z.y = 0; z.z = 0; z.w = 0;
            *(uint4*)(sm + off) = z;
        }
        __syncthreads();
    }
    const size_t tb = (size_t)(b * 265 + tt) * 8192;
#pragma unroll
    for (int i2 = 0; i2 < 4; ++i2) {
        const int o = (i2 * 256 + t) * 8;
        const int slot2 = o >> 9;
        const int idx = (o >> 3) & 63;
        const int jb = (slot2 >> 3) * 16 + (idx >> 5) * 8;
        const int d = (slot2 & 7) * 32 + (idx & 31);
        u32 wpk[4];
#pragma unroll
        for (int e2 = 0; e2 < 4; ++e2) {
            const int j1 = jb + e2 * 2, j2 = j1 + 1;
            const u16 a0 = *(const u16*)(sm + j1 * 512 + (((d >> 3) ^ (j1 & 31)) << 4) + (d & 7) * 2);
            const u16 a1 = *(const u16*)(sm + j2 * 512 + (((d >> 3) ^ (j2 & 31)) << 4) + (d & 7) * 2);
            wpk[e2] = (u32)a0 | ((u32)a1 << 16);
        }
        uint4 pk; pk.x = wpk[0]; pk.y = wpk[1]; pk.z = wpk[2]; pk.w = wpk[3];
        *(uint4*)(vpack + tb + o) = pk;
    }
}

// ---------------- compressed flash attention ----------------
// Block = 4 waves, Q-tile 128. K staged straight from row-major qkb (gathered rows,
// XOR-swizzled); V staged linearly from vpack; double-buffered 64KB.
__global__ __launch_bounds__(256)
void attn_kernel(const u16* __restrict__ qkb, const u16* __restrict__ vpack,
                 u16* __restrict__ attnb, u16* __restrict__ partLo, u16* __restrict__ partHi,
                 float* __restrict__ mlbuf) {
    __shared__ __align__(16) unsigned char sm[65536];

    const int b = blockIdx.x & 1;
    int rb = blockIdx.x >> 1;
    int colg = 0, exb = 0, p = 0;
    for (; p < 24; ++p) {
        if (rb >= T_cht[p]) { rb -= T_cht[p]; colg += T_nc[p]; exb += T_ext[p]; }
        else break;
    }
    int col = 0, chunk = 0, ntB = 0, tA0 = 0, nt = 0;
    for (int c = T_nc[p] - 1; c >= 0; --c) {
        int nb, ta, n;
        col_geom(p, c, nb, ta, n);
        const int nch2 = (n + 7) >> 3;
        if (rb < nch2) { col = c; chunk = rb; ntB = nb; tA0 = ta; nt = n; break; }
        rb -= nch2; ++colg; exb += nch2 - 1;
    }
    const int nch = (nt + 7) >> 3;
    const int h = T_h[p], g = T_g[p];
    const int s = (h == 0) ? 1 : (h == 1) ? 3 : (h == 2) ? 7 : 13;
    const int LQ = T_LQ[p];
    const int cB = T_cB[p], cA = T_cA[p], dA = T_dA[p];
    const int ktB = T_ktB[p], ktA = T_ktA[p];
    const int LKB = T_LkB[p], LKA = T_LkA[p];
    // token-residue classes of the two key segments
    const int clsBt = (h == 0) ? 0 : (h == 1) ? (g % 3) : (h == 2) ? ((g + 1) % 7) : ((g + 9) % 13);
    const int clsAt = (h == 0) ? 0 : (h == 1) ? ((g + 2) % 3) : (h == 2) ? ((g + 5) % 7) : ((g + 3) % 13);
    const int PBi = b * 265;

    const int t = threadIdx.x;
    const int w = t >> 6;
    const int l = t & 63;
    const int l31 = l & 31, h5 = l >> 5;
    const int m = (col << 7) + (w << 5) + l31;     // compressed query index
    const int mq = (m < LQ) ? m : (LQ - 1);
    const float c2 = 0.09016844f;                  // (1/16) * log2(e)

    // Q fragments directly from qkb (token g + mq*s)
    bf16x8 qf[16];
    {
        const u16* qb = qkb + (size_t)((b * 2048 + g + mq * s) * 1024 + h * 256) + h5 * 8;
#pragma unroll
        for (int dc = 0; dc < 16; ++dc)
            qf[dc] = *(const bf16x8*)(qb + dc * 16);
    }

    auto stageT = [&](int tv, int buf) {
        int j0k, clsT, LKk, tileV;
        if (tv < ntB) { j0k = tv << 5; clsT = clsBt; LKk = LKB; tileV = ktB + tv; }
        else { const int ta = tA0 + tv - ntB; j0k = ta << 5; clsT = clsAt; LKk = LKA; tileV = ktA + ta; }
        unsigned char* Kd = sm + buf * 32768;
        unsigned char* Vd = Kd + 16384;
#pragma unroll
        for (int i2 = 0; i2 < 4; ++i2) {
            const int pp = i2 * 4096 + t * 16;
            const int j = pp >> 9;
            const int cb = (pp & 511) ^ ((j & 31) << 4);
            int jj = j0k + j; if (jj > LKk - 1) jj = LKk - 1;
            const int tok = clsT + jj * s;
            g2l16(qkb + (size_t)((b * 2048 + tok) * 1024 + h * 256) + (cb >> 1), Kd + pp);
        }
        const size_t vtb = (size_t)(PBi + tileV) * 8192;
#pragma unroll
        for (int i2 = 0; i2 < 4; ++i2) {
            const int off = i2 * 4096 + t * 16;
            g2l16(vpack + vtb + (off >> 1), Vd + off);
        }
    };

    const int tt0 = chunk * 8;
    int tt1 = tt0 + 8; if (tt1 > nt) tt1 = nt;

    f32x16 o[8] = {};
    float mrun = -3.0e38f, lrun = 0.0f;

    stageT(tt0, 0);
    asm volatile("s_waitcnt vmcnt(0)" ::: "memory");
    __syncthreads();

    int buf = 0;
    for (int tv = tt0; tv < tt1; ++tv) {
        if (tv + 1 < tt1) stageT(tv + 1, buf ^ 1);

        int j0, lo, hi;
        if (tv < ntB) { j0 = tv << 5; lo = -100000; hi = cB; }
        else { const int ta = tA0 + tv - ntB; j0 = ta << 5; lo = cA; hi = dA; }

        const unsigned char* Kb = sm + buf * 32768;
        const unsigned char* Vb = Kb + 16384;
        const int lslot = (h5 * 32 + l31) * 16;

        // S^T = K * Q^T  (K row l31, swizzled slots)
        f32x16 sacc = {};
#pragma unroll
        for (int dc = 0; dc < 16; ++dc) {
            const bf16x8 kf = *(const bf16x8*)(Kb + l31 * 512 + (((dc * 2 + h5) ^ l31) << 4));
            sacc = __builtin_amdgcn_mfma_f32_32x32x16_bf16(kf, qf[dc], sacc, 0, 0, 0);
        }

        // mask + online softmax (lane-local; e = j - m)
        const int ebase = j0 - m;
        float sv[16];
        float tmax = -3.0e38f;
#pragma unroll
        for (int r = 0; r < 16; ++r) {
            const int km = (r & 3) + 8 * (r >> 2) + 4 * h5;
            const int e = ebase + km;
            const bool ok = (e >= lo) && (e < hi);
            sv[r] = ok ? sacc[r] : -3.0e38f;
            tmax = fmaxf(tmax, sv[r]);
        }
        tmax = fmaxf(tmax, __shfl_xor(tmax, 32, 64));
        if (!__all(tmax <= mrun + 8.0f)) {     // defer-max
            const float mnew = fmaxf(mrun, tmax);
            const float fsc = __builtin_amdgcn_exp2f((mrun - mnew) * c2);
            lrun *= fsc;
#pragma unroll
            for (int ch = 0; ch < 8; ++ch)
#pragma unroll
                for (int r = 0; r < 16; ++r)
                    o[ch][r] *= fsc;
            mrun = mnew;
        }
        float psum = 0.0f;
#pragma unroll
        for (int r = 0; r < 16; ++r) {
            const float pv = (sv[r] > -1.0e37f) ? __builtin_amdgcn_exp2f((sv[r] - mrun) * c2) : 0.0f;
            sv[r] = pv;
            psum += pv;
        }
        lrun += psum;

        // P -> bf16 fragments: cvt_pk + permlane32_swap
        uint32_t w0, w1, w2, w3, w4, w5, w6, w7;
        asm("v_cvt_pk_bf16_f32 %0,%1,%2" : "=v"(w0) : "v"(sv[0]),  "v"(sv[1]));
        asm("v_cvt_pk_bf16_f32 %0,%1,%2" : "=v"(w1) : "v"(sv[2]),  "v"(sv[3]));
        asm("v_cvt_pk_bf16_f32 %0,%1,%2" : "=v"(w2) : "v"(sv[4]),  "v"(sv[5]));
        asm("v_cvt_pk_bf16_f32 %0,%1,%2" : "=v"(w3) : "v"(sv[6]),  "v"(sv[7]));
        asm("v_cvt_pk_bf16_f32 %0,%1,%2" : "=v"(w4) : "v"(sv[8]),  "v"(sv[9]));
        asm("v_cvt_pk_bf16_f32 %0,%1,%2" : "=v"(w5) : "v"(sv[10]), "v"(sv[11]));
        asm("v_cvt_pk_bf16_f32 %0,%1,%2" : "=v"(w6) : "v"(sv[12]), "v"(sv[13]));
        asm("v_cvt_pk_bf16_f32 %0,%1,%2" : "=v"(w7) : "v"(sv[14]), "v"(sv[15]));
        asm("v_permlane32_swap_b32 %0, %1" : "+v"(w0), "+v"(w2));
        asm("v_permlane32_swap_b32 %0, %1" : "+v"(w1), "+v"(w3));
        asm("v_permlane32_swap_b32 %0, %1" : "+v"(w4), "+v"(w6));
        asm("v_permlane32_swap_b32 %0, %1" : "+v"(w5), "+v"(w7));
        union { uint32_t u[4]; bf16x8 v; } p0u, p1u;
        p0u.u[0] = w0; p0u.u[1] = w1; p0u.u[2] = w2; p0u.u[3] = w3;
        p1u.u[0] = w4; p1u.u[1] = w5; p1u.u[2] = w6; p1u.u[3] = w7;

        // O^T += V^T * P^T
#pragma unroll
        for (int kk = 0; kk < 2; ++kk) {
            const bf16x8 pf = kk ? p1u.v : p0u.v;
#pragma unroll
            for (int ch = 0; ch < 8; ++ch) {
                const bf16x8 vf = *(const bf16x8*)(Vb + (kk * 8 + ch) * 1024 + lslot);
                o[ch] = __builtin_amdgcn_mfma_f32_32x32x16_bf16(vf, pf, o[ch], 0, 0, 0);
            }
        }

        asm volatile("s_waitcnt vmcnt(0)" ::: "memory");
        __syncthreads();
        buf ^= 1;
    }

    lrun += __shfl_xor(lrun, 32, 64);

    float scale = 1.0f;
    u16* ab;
    const int qm = (w << 5) + l31;
    if (nch == 1) {
        scale = (lrun > 0.0f) ? 1.0f / lrun : 0.0f;
        ab = attnb + ((size_t)(b * 2048 + g + m * s)) * 1024 + h * 256;
    } else {
        if (h5 == 0 && m < LQ) {
            const int colid = b * 81 + colg;
            mlbuf[(size_t)((colid * 8 + chunk) * 256) + qm * 2]     = mrun;
            mlbuf[(size_t)((colid * 8 + chunk) * 256) + qm * 2 + 1] = lrun;
        }
        if (chunk == 0)
            ab = attnb + ((size_t)(b * 2048 + g + m * s)) * 1024 + h * 256;
        else
            ab = partO_addr(partLo, partHi, b * 94 + exb + chunk - 1) + (size_t)qm * 256;
    }

    if (m < LQ) {
#pragma unroll
        for (int ch = 0; ch < 8; ++ch) {
#pragma unroll
            for (int g2 = 0; g2 < 4; ++g2) {
                ushort4 wv4;
                wv4.x = f2bf(o[ch][g2 * 4 + 0] * scale);
                wv4.y = f2bf(o[ch][g2 * 4 + 1] * scale);
                wv4.z = f2bf(o[ch][g2 * 4 + 2] * scale);
                wv4.w = f2bf(o[ch][g2 * 4 + 3] * scale);
                *(ushort4*)(ab + ch * 32 + 8 * g2 + 4 * h5) = wv4;
            }
        }
    }
}

// ---------------- combine chunked columns ----------------
__global__ __launch_bounds__(256)
void combine_kernel(const u16* __restrict__ partLo, const u16* __restrict__ partHi,
                    const float* __restrict__ mlbuf, u16* __restrict__ attnb) {
    const int b = blockIdx.x & 1;
    int rb = blockIdx.x >> 1;
    int colg = 0, exb = 0, p = 0;
    for (; p < 24; ++p) {
        if (rb >= T_mcc[p]) { rb -= T_mcc[p]; colg += T_nc[p]; exb += T_ext[p]; }
        else break;
    }
    int col = 0, nch = 0;
    for (int c = T_nc[p] - 1; c >= 0; --c) {
        int nb, ta, n;
        col_geom(p, c, nb, ta, n);
        const int nc2 = (n + 7) >> 3;
        if (nc2 > 1) {
            if (rb == 0) { col = c; nch = nc2; break; }
            --rb;
        }
        ++colg; exb += nc2 - 1;
    }
    const int h = T_h[p], g = T_g[p];
    const int s = (h == 0) ? 1 : (h == 1) ? 3 : (h == 2) ? 7 : 13;
    const int LQ = T_LQ[p];
    const int colid = b * 81 + colg;
    const float c2 = 0.09016844f;

    const int t = threadIdx.x;
    const int q = t >> 1, dpart = (t & 1) * 128;
    const int m = (col << 7) + q;

    float mj[8], lj[8];
#pragma unroll
    for (int j5 = 0; j5 < 8; ++j5) {
        if (j5 < nch) {
            mj[j5] = mlbuf[(size_t)((colid * 8 + j5) * 256) + q * 2];
            lj[j5] = mlbuf[(size_t)((colid * 8 + j5) * 256) + q * 2 + 1];
        } else { mj[j5] = -3.0e38f; lj[j5] = 0.0f; }
    }
    float M = -3.0e38f;
#pragma unroll
    for (int j5 = 0; j5 < 8; ++j5) if (j5 < nch) M = fmaxf(M, mj[j5]);
    float L = 0.0f, al[8];
#pragma unroll
    for (int j5 = 0; j5 < 8; ++j5) {
        al[j5] = (j5 < nch) ? __builtin_amdgcn_exp2f((mj[j5] - M) * c2) : 0.0f;
        L += lj[j5] * al[j5];
    }
    const float inv = (L > 0.0f) ? 1.0f / L : 0.0f;
#pragma unroll
    for (int j5 = 0; j5 < 8; ++j5) al[j5] *= inv;

    u16* dst = attnb + ((size_t)(b * 2048 + g + m * s)) * 1024 + h * 256 + dpart;

    for (int ss = 0; ss < 4; ++ss) {
        float acc32[32];
#pragma unroll
        for (int e = 0; e < 32; ++e) acc32[e] = 0.0f;
#pragma unroll
        for (int j5 = 0; j5 < 8; ++j5) {
            if (j5 >= nch) continue;
            const u16* src = (j5 == 0)
                ? (dst + ss * 32)
                : (partO_addr_c(partLo, partHi, b * 94 + exb + j5 - 1) + (size_t)q * 256 + dpart + ss * 32);
            const float sc = al[j5];
#pragma unroll
            for (int w4 = 0; w4 < 4; ++w4) {
                const uint4 pk = *(const uint4*)(src + w4 * 8);
                const u32 ww[4] = { pk.x, pk.y, pk.z, pk.w };
#pragma unroll
                for (int e = 0; e < 4; ++e) {
                    union { u32 u; float f; } lo2, hi2;
                    lo2.u = ww[e] << 16;
                    hi2.u = ww[e] & 0xffff0000u;
                    acc32[w4 * 8 + e * 2]     += sc * lo2.f;
                    acc32[w4 * 8 + e * 2 + 1] += sc * hi2.f;
                }
            }
        }
        if (m < LQ) {
#pragma unroll
            for (int w4 = 0; w4 < 4; ++w4) {
                uint4 pk;
                pk.x = (u32)f2bf(acc32[w4 * 8 + 0]) | ((u32)f2bf(acc32[w4 * 8 + 1]) << 16);
                pk.y = (u32)f2bf(acc32[w4 * 8 + 2]) | ((u32)f2bf(acc32[w4 * 8 + 3]) << 16);
                pk.z = (u32)f2bf(acc32[w4 * 8 + 4]) | ((u32)f2bf(acc32[w4 * 8 + 5]) << 16);
                pk.w = (u32)f2bf(acc32[w4 * 8 + 6]) | ((u32)f2bf(acc32[w4 * 8 + 7]) << 16);
                *(uint4*)(dst + ss * 32 + w4 * 8) = pk;
            }
        }
    }
}

// ---------------- output GEMM: out = attnb @ Wo^T + bo (f32) ----------------
// BM=128 BN=64, grid 512.
__global__ __launch_bounds__(256)
void gemm_out(const u16* __restrict__ A, const u16* __restrict__ Bw,
              const float* __restrict__ bias, float* __restrict__ outp) {
    __shared__ __align__(16) u16 As[2][4096], Bs[2][2048];
    const int bid = blockIdx.x;
    const int m0 = (bid >> 4) * 128;
    const int n0 = (bid & 15) * 64;
    const int t = threadIdx.x;
    const int lane = t & 63;
    const int wid = t >> 6;
    const int wr = wid >> 1, wc = wid & 1;
    const int l15 = lane & 15, l4 = lane >> 4;

    f32x4 acc[4][2] = {};

    auto stage = [&](int buf, int kt) {
        const int kbase = kt * 32;
#pragma unroll
        for (int c2 = 0; c2 < 2; ++c2) {
            const int pp = c2 * 4096 + t * 16;
            g2l16(A + (size_t)(m0 + (pp >> 6)) * 1024 + kbase + ((pp & 63) >> 1), (char*)As[buf] + pp);
        }
        const int pb = t * 16;
        g2l16(Bw + (size_t)(n0 + (pb >> 6)) * 1024 + kbase + ((pb & 63) >> 1), (char*)Bs[buf] + pb);
    };

    stage(0, 0);
    asm volatile("s_waitcnt vmcnt(0)" ::: "memory");
    __syncthreads();

    int cur = 0;
    for (int kt = 0; kt < 32; ++kt) {
        if (kt + 1 < 32) stage(cur ^ 1, kt + 1);
        bf16x8 af[4], bfr[2];
#pragma unroll
        for (int mi = 0; mi < 4; ++mi)
            af[mi] = *(const bf16x8*)((const char*)As[cur] + (wr * 64 + mi * 16 + l15) * 64 + l4 * 16);
#pragma unroll
        for (int ni = 0; ni < 2; ++ni)
            bfr[ni] = *(const bf16x8*)((const char*)Bs[cur] + (wc * 32 + ni * 16 + l15) * 64 + l4 * 16);
#pragma unroll
        for (int mi = 0; mi < 4; ++mi)
#pragma unroll
            for (int ni = 0; ni < 2; ++ni)
                acc[mi][ni] = __builtin_amdgcn_mfma_f32_16x16x32_bf16(af[mi], bfr[ni], acc[mi][ni], 0, 0, 0);
        asm volatile("s_waitcnt vmcnt(0)" ::: "memory");
        __syncthreads();
        cur ^= 1;
    }

    const int mbase = m0 + wr * 64 + l4 * 4;
    const int nbase = n0 + wc * 32 + l15;
#pragma unroll
    for (int ni = 0; ni < 2; ++ni) {
        const int n = nbase + ni * 16;
        const float bv = bias[n];
#pragma unroll
        for (int mi = 0; mi < 4; ++mi) {
            const int mrow = mbase + mi * 16;
#pragma unroll
            for (int r = 0; r < 4; ++r)
                outp[(size_t)(mrow + r) * 1024 + n] = acc[mi][ni][r] + bv;
        }
    }
}

extern "C" void kernel_launch(void* const* d_in, const int* in_sizes, int n_in,
                              void* d_out, int out_size, void* d_ws, size_t ws_size,
                              hipStream_t stream) {
    const float* x   = (const float*)d_in[0];
    const float* Wqk = (const float*)d_in[1];
    const float* bqk = (const float*)d_in[2];
    const float* Wv  = (const float*)d_in[3];
    const float* bv  = (const float*)d_in[4];
    const float* Wo  = (const float*)d_in[5];
    const float* bo  = (const float*)d_in[6];
    float* out = (float*)d_out;

    u16* ws     = (u16*)d_ws;
    u16* xb     = ws;             // 4194304 (dead after gemm_qkv -> attnb overlay)
    u16* wqkb   = ws + 4194304;   // 1048576 (dead after gemm_qkv -> partO hi overlay)
    u16* wvb    = ws + 5242880;   // 1048576 (dead after gemm_qkv)
    u16* wob    = ws + 6291456;   // 1048576 (live until gemm_out)
    u16* qkb    = ws + 7340032;   // 4194304 (live through attn: Q + K source)
    u16* vb     = ws + 11534336;  // 4194304 (dead after repack_v -> partO lo overlay)
    u16* vpack  = ws + 15728640;  // 4341760  (end 20070400 u16 = 40.1 MB)
    u16* attnb  = ws;             // overlays xb
    u16* partLo = ws + 11534336;  // 128 slots x 32768 (overlays vb)
    u16* partHi = ws + 4194304;   // 60 slots x 32768 (overlays wqkb+wvb)
    float* mlbuf = (float*)d_out; // d_out dead until gemm_out

    cvt_kernel<<<7168, 256, 0, stream>>>(x, Wqk, Wv, Wo, ws);
    gemm_qkv<<<512, 256, 0, stream>>>(xb, wqkb, wvb, bqk, bv, qkb, vb);
    repack_v<<<530, 256, 0, stream>>>(vb, vpack);
    attn_kernel<<<350, 256, 0, stream>>>(qkb, vpack, attnb, partLo, partHi, mlbuf);
    combine_kernel<<<80, 256, 0, stream>>>(partLo, partHi, mlbuf, attnb);
    gemm_out<<<512, 256, 0, stream>>>(attnb, wob, bo, out);
}